// Round 6
// baseline (5072.424 us; speedup 1.0000x reference)
//
#include <hip/hip_runtime.h>

#define H      51
#define T_IN   512
#define T_TOT  576
#define P52    52
#define MROWS  204
// LDS float offsets: three full 204x51 matrices (pitch 52, k=51 zero-padded)
// + gate-exchange buffer [4 local elems][4 gates][52].
#define OFF_W1  0
#define OFF_WI3 (MROWS * P52)
#define OFF_WH3 (2 * MROWS * P52)
#define OFF_GB  (3 * MROWS * P52)
#define LDSFL   (OFF_GB + 4 * 4 * P52)   // 32,656 floats = 130,624 B -> 1 block/CU

__device__ __forceinline__ float bf2f(unsigned short u) {
    return __uint_as_float(((unsigned int)u) << 16);
}
__device__ __forceinline__ unsigned short f2bf(float f) {
    unsigned int u = __float_as_uint(f);
    u += 0x7fffu + ((u >> 16) & 1u);
    return (unsigned short)(u >> 16);
}
__device__ __forceinline__ float wget(const void* p, int i, bool is16) {
    return is16 ? bf2f(((const unsigned short*)p)[i]) : ((const float*)p)[i];
}
__device__ __forceinline__ float rl(float v, int k) {
    return __uint_as_float((unsigned int)__builtin_amdgcn_readlane((int)__float_as_uint(v), k));
}
__device__ __forceinline__ float sigm(float x) {
    x = fminf(fmaxf(x, -30.f), 30.f);
    return 1.f / (1.f + __expf(-x));
}
__device__ __forceinline__ float tanh_f(float x) {
    x = fminf(fmaxf(x, -15.f), 15.f);
    float e = __expf(2.f * x);
    return (e - 1.f) / (e + 1.f);
}
__device__ __forceinline__ float f4e(float4 v, int i) {
    return i == 0 ? v.x : i == 1 ? v.y : i == 2 ? v.z : v.w;
}

#define RED(sv) { sv += __shfl_xor(sv, 32, 64); sv += __shfl_xor(sv, 16, 64); \
    sv += __shfl_xor(sv, 8, 64); sv += __shfl_xor(sv, 4, 64); \
    sv += __shfl_xor(sv, 2, 64); sv += __shfl_xor(sv, 1, 64); }

// Round-6 restructure: j/gate-split instead of k-split.
// Grid 256 blocks x 8 waves; block = 4 batch elements; 1 block/CU (130.6 KB LDS).
// Wave w: gate g = w&3, elem-pair ep = w>>2 (local elems 2ep, 2ep+1).
// Lane j computes gate g of output row j COMPLETELY (full k dot-product) ->
//   * no cross-wave partial reduction (the gate value is final in one wave),
//   * exchange = 2 ds_write_b32 + 4 ds_read_b32 broadcasts,
//   * UPD redundant per elem-pair in all its 4 gate-waves -> h stays in
//     registers of every wave, lane-positioned for next layer's readlane,
//   * all waves symmetric -> minimal barrier skew; barriers bracket only the
//     tiny gate-write phase (FMA -> bar(WAR) -> write -> bar(RAW) -> UPD).
// Registers: persistent weights 102 (Wih2+Whh2 rows) vs 169 in the k-split --
// well below the spill cliff that killed rounds 1/3/4 (WRITE_SIZE canary).
// LDS matrices: Whh1, Wih3, Whh3 (each wave reads its own gate-row slice).
extern "C" __global__ void __launch_bounds__(512)
__attribute__((amdgpu_waves_per_eu(2, 2)))
lstm3_kernel(const void* g_in,  const void* g_Wih1, const void* g_Whh1,
             const void* g_bih1, const void* g_bhh1,
             const void* g_Wih2, const void* g_Whh2, const void* g_bih2, const void* g_bhh2,
             const void* g_Wih3, const void* g_Whh3, const void* g_bih3, const void* g_bhh3,
             const void* g_Wlin, const void* g_blin, void* g_out)
{
    extern __shared__ float smem[];

    const int tid  = threadIdx.x;
    const int lane = tid & 63;
    const int w    = tid >> 6;          // 0..7
    const int g    = w & 3;             // gate (i,f,g,o)
    const int ep   = w >> 2;            // elem-pair 0/1
    const int jeff = (lane < H) ? lane : (H - 1);
    const int e0   = blockIdx.x * 4 + 2 * ep;   // first global elem of my pair
    const int el0  = 2 * ep;                    // first local elem (0..3)

    // ---- dtype sniff (proven: resolves fp32 on this harness)
    bool is16 = true;
    {
        const unsigned short* p = (const unsigned short*)g_Wih1;
        for (int i = 0; i < 204; ++i) {
            float v = fabsf(bf2f(p[i]));
            if (!(v < 0.2f)) is16 = false;
        }
    }

    // ---- LDS staging: Whh1, Wih3, Whh3 (row-major, pitch 52, k=51 pad 0)
    for (int i = tid; i < MROWS * P52; i += 512) {
        int r = i / P52, k = i - r * P52;
        smem[OFF_W1  + i] = (k < H) ? wget(g_Whh1, r * H + k, is16) : 0.f;
        smem[OFF_WI3 + i] = (k < H) ? wget(g_Wih3, r * H + k, is16) : 0.f;
        smem[OFF_WH3 + i] = (k < H) ? wget(g_Whh3, r * H + k, is16) : 0.f;
    }
    __syncthreads();

    // ---- register weights: my gate's full rows of Wih2, Whh2 (102 floats)
    float wih2[H], whh2[H];
#pragma unroll
    for (int k = 0; k < H; ++k) {
        wih2[k] = wget(g_Wih2, (g * H + jeff) * H + k, is16);
        whh2[k] = wget(g_Whh2, (g * H + jeff) * H + k, is16);
    }
    const float b1 = wget(g_bih1, g*H+jeff, is16) + wget(g_bhh1, g*H+jeff, is16);
    const float b2 = wget(g_bih2, g*H+jeff, is16) + wget(g_bhh2, g*H+jeff, is16);
    const float b3 = wget(g_bih3, g*H+jeff, is16) + wget(g_bhh3, g*H+jeff, is16);
    const float wi1 = wget(g_Wih1, g*H+jeff, is16);
    const float wlinr = (lane < H) ? wget(g_Wlin, lane, is16) : 0.f;
    const float blinr = wget(g_blin, 0, is16);

    const float4* A1  = (const float4*)(smem + OFF_W1  + (g * H + jeff) * P52);
    const float4* AI3 = (const float4*)(smem + OFF_WI3 + (g * H + jeff) * P52);
    const float4* AH3 = (const float4*)(smem + OFF_WH3 + (g * H + jeff) * P52);
    float* gb = smem + OFF_GB;

    float h1_0=0.f,h1_1=0.f,h2_0=0.f,h2_1=0.f,h3_0=0.f,h3_1=0.f;  // my pair only
    float c1_0=0.f,c1_1=0.f,c2_0=0.f,c2_1=0.f,c3_0=0.f,c3_1=0.f;
    float xf0=0.f,xf1=0.f;

    const unsigned short* in16 = (const unsigned short*)g_in;
    const float*          in32 = (const float*)g_in;
    unsigned short* o16a = (unsigned short*)g_out + (size_t)(e0+0)*T_TOT;
    unsigned short* o16b = (unsigned short*)g_out + (size_t)(e0+1)*T_TOT;
    float* o32a = (float*)g_out + (size_t)(e0+0)*T_TOT;
    float* o32b = (float*)g_out + (size_t)(e0+1)*T_TOT;

    // redundant cell update for one local elem (4 broadcast reads + activations)
#define UPD(el, cm, hv) { \
    int b_ = (el) * 4 * P52 + jeff; \
    float gi_ = gb[b_], gf_ = gb[b_ + P52], gg_ = gb[b_ + 2*P52], go_ = gb[b_ + 3*P52]; \
    float i_ = sigm(gi_), f_ = sigm(gf_), t_ = tanh_f(gg_), o_ = sigm(go_); \
    cm = f_ * cm + i_ * t_; \
    hv = o_ * tanh_f(cm); }

    // write my final gate values for both elems of my pair
#define WRGATES() { \
    if (lane < H) { \
        gb[(el0*4 + g)*P52 + lane]       = a0; \
        gb[((el0+1)*4 + g)*P52 + lane]   = a1; \
    } }

#pragma clang loop unroll(disable)
    for (int t = 0; t < T_TOT; ++t) {
        float x0, x1;
        if (t < T_IN) {
            if (is16) {
                x0 = bf2f(in16[(size_t)(e0+0)*T_IN + t]);
                x1 = bf2f(in16[(size_t)(e0+1)*T_IN + t]);
            } else {
                x0 = in32[(size_t)(e0+0)*T_IN + t];
                x1 = in32[(size_t)(e0+1)*T_IN + t];
            }
        } else { x0 = xf0; x1 = xf1; }

        // ---------------- layer 1: b1 + Wih1*x + Whh1@h1_old (LDS) ----------------
        float a0 = fmaf(wi1, x0, b1), a1 = fmaf(wi1, x1, b1);
#pragma unroll
        for (int b = 0; b < 13; ++b) {
            float4 u = A1[b];
#pragma unroll
            for (int i = 0; i < 4; ++i) {
                int k = 4*b + i;                       // k=51 hits the 0 pad
                float s0 = rl(h1_0, k), s1 = rl(h1_1, k);
                a0 = fmaf(f4e(u,i), s0, a0); a1 = fmaf(f4e(u,i), s1, a1);
            }
        }
        __syncthreads();                               // WAR: prior gb reads done
        WRGATES()
        __syncthreads();                               // RAW
        UPD(el0,   c1_0, h1_0)
        UPD(el0+1, c1_1, h1_1)

        // ---------------- layer 2: b2 + Wih2@h1_new + Whh2@h2_old (regs) ----------
        a0 = b2; a1 = b2;
#pragma unroll
        for (int k = 0; k < H; ++k) {
            float s0 = rl(h1_0, k), s1 = rl(h1_1, k);
            float r0 = rl(h2_0, k), r1 = rl(h2_1, k);
            a0 = fmaf(wih2[k], s0, a0); a1 = fmaf(wih2[k], s1, a1);
            a0 = fmaf(whh2[k], r0, a0); a1 = fmaf(whh2[k], r1, a1);
        }
        __syncthreads();                               // WAR
        WRGATES()
        __syncthreads();                               // RAW
        UPD(el0,   c2_0, h2_0)
        UPD(el0+1, c2_1, h2_1)

        // ---------------- layer 3: b3 + Wih3@h2_new + Whh3@h3_old (LDS x2) --------
        a0 = b3; a1 = b3;
#pragma unroll
        for (int b = 0; b < 13; ++b) {
            float4 u = AI3[b], v = AH3[b];
#pragma unroll
            for (int i = 0; i < 4; ++i) {
                int k = 4*b + i;
                float s0 = rl(h2_0, k), s1 = rl(h2_1, k);
                float r0 = rl(h3_0, k), r1 = rl(h3_1, k);
                a0 = fmaf(f4e(u,i), s0, a0); a1 = fmaf(f4e(u,i), s1, a1);
                a0 = fmaf(f4e(v,i), r0, a0); a1 = fmaf(f4e(v,i), r1, a1);
            }
        }
        __syncthreads();                               // WAR
        WRGATES()
        __syncthreads();                               // RAW
        UPD(el0,   c3_0, h3_0)
        UPD(el0+1, c3_1, h3_1)

        // ---------------- head: redundant per pair (h3 in-register) ---------------
        float s0 = wlinr * h3_0; RED(s0) float ov0 = s0 + blinr;
        float s1 = wlinr * h3_1; RED(s1) float ov1 = s1 + blinr;
        xf0 = ov0; xf1 = ov1;
        if (g == 0 && lane == 0) {
            if (is16) { o16a[t] = f2bf(ov0); o16b[t] = f2bf(ov1); }
            else      { o32a[t] = ov0;       o32b[t] = ov1; }
        }
    }
}

extern "C" void kernel_launch(void* const* d_in, const int* in_sizes, int n_in,
                              void* d_out, int out_size, void* d_ws, size_t ws_size,
                              hipStream_t stream) {
    (void)in_sizes; (void)n_in; (void)d_ws; (void)ws_size; (void)out_size;
    size_t shmem = LDSFL * sizeof(float);   // 130,624 B -> 1 block/CU
    hipFuncSetAttribute((const void*)lstm3_kernel,
                        hipFuncAttributeMaxDynamicSharedMemorySize, (int)shmem);
    lstm3_kernel<<<dim3(256), dim3(512), shmem, stream>>>(
        d_in[0],  d_in[1],  d_in[2],  d_in[3],  d_in[4],
        d_in[5],  d_in[6],  d_in[7],  d_in[8],
        d_in[9],  d_in[10], d_in[11], d_in[12],
        d_in[13], d_in[14], d_out);
}

// Round 7
// 3348.197 us; speedup vs baseline: 1.5150x; 1.5150x over previous
//
#include <hip/hip_runtime.h>

#define H      51
#define T_IN   512
#define T_TOT  576
#define PITCH  52
// float offsets within smem. ONE shared copy of the LDS weight matrices serves
// both 4-wave teams; per-team partial/h buffers follow.
#define OFF_W1 0                           // Whh1: 204 x 52 = 10,608
#define OFF_W3 (204 * PITCH)               // Wih3 gates f,g,o: 153 x 52 = 7,956
#define OFF_P  (OFF_W3 + 153 * PITCH)      // partials: [team][2 elem][4 wave][52] float4
#define SZ_PT  (2 * 4 * PITCH * 4)         // 1,664 floats per team
#define OFF_H  (OFF_P + 2 * SZ_PT)         // h broadcast: [team][2 elem][52]
#define LDSFL  (OFF_H + 2 * 2 * PITCH)     // 22,100 floats = 88,400 B -> 1 block/CU

__device__ __forceinline__ float bf2f(unsigned short u) {
    return __uint_as_float(((unsigned int)u) << 16);
}
__device__ __forceinline__ unsigned short f2bf(float f) {
    unsigned int u = __float_as_uint(f);
    u += 0x7fffu + ((u >> 16) & 1u);
    return (unsigned short)(u >> 16);
}
__device__ __forceinline__ float wget(const void* p, int i, bool is16) {
    return is16 ? bf2f(((const unsigned short*)p)[i]) : ((const float*)p)[i];
}
__device__ __forceinline__ float rl(float v, int k) {
    return __uint_as_float((unsigned int)__builtin_amdgcn_readlane((int)__float_as_uint(v), k));
}
__device__ __forceinline__ float sigm(float x) {
    x = fminf(fmaxf(x, -30.f), 30.f);
    return 1.f / (1.f + __expf(-x));
}
__device__ __forceinline__ float tanh_f(float x) {
    x = fminf(fmaxf(x, -15.f), 15.f);
    float e = __expf(2.f * x);
    return (e - 1.f) / (e + 1.f);
}
__device__ __forceinline__ float f4e(float4 v, int i) {
    return i == 0 ? v.x : i == 1 ? v.y : i == 2 ? v.z : v.w;
}

#define L13(M) M(0) M(1) M(2) M(3) M(4) M(5) M(6) M(7) M(8) M(9) M(10) M(11) M(12)

#define RED(sv) { sv += __shfl_xor(sv, 32, 64); sv += __shfl_xor(sv, 16, 64); \
    sv += __shfl_xor(sv, 8, 64); sv += __shfl_xor(sv, 4, 64); \
    sv += __shfl_xor(sv, 2, 64); sv += __shfl_xor(sv, 1, 64); }

// Round-7: the PROVEN round-0 k-split structure, re-packed as ONE 8-wave block
// per CU. Block = 2 independent 4-wave teams; team T handles batch elems
// (blockIdx*4 + 2T, +2T+1) with per-wave code IDENTICAL to round-0 (same
// register footprint -> spill-safe). The teams share a single LDS copy of the
// weight matrices (the 74 KB that made 2x81.3KB blocks not reliably co-resident:
// occupancy counter read 20.8% vs the calibrated 25% of guaranteed residency --
// i.e. part of the 512-block grid was serialized waiting for LDS). Grid 256 =
// one block per CU, LDS 88.4 KB -> guaranteed single-round execution, same
// 2 waves/SIMD. Cost: teams share __syncthreads (symmetric work, small skew).
extern "C" __global__ void __launch_bounds__(512)
__attribute__((amdgpu_waves_per_eu(2, 2)))
lstm3_kernel(const void* g_in,  const void* g_Wih1, const void* g_Whh1,
             const void* g_bih1, const void* g_bhh1,
             const void* g_Wih2, const void* g_Whh2, const void* g_bih2, const void* g_bhh2,
             const void* g_Wih3, const void* g_Whh3, const void* g_bih3, const void* g_bhh3,
             const void* g_Wlin, const void* g_blin, void* g_out)
{
    extern __shared__ float smem[];

    const int tid  = threadIdx.x;
    const int lane = tid & 63;
    const int wid8 = tid >> 6;          // 0..7
    const int team = wid8 >> 2;         // 0,1
    const int wid  = wid8 & 3;          // role within team (as round-0's wid)
    const int eb   = blockIdx.x * 4 + team * 2;
    const int jeff = (lane < H) ? lane : (H - 1);

    // ---- dtype sniff (proven: resolves fp32 on this harness)
    bool is16 = true;
    {
        const unsigned short* p = (const unsigned short*)g_Wih1;
        for (int i = 0; i < 204; ++i) {
            float v = fabsf(bf2f(p[i]));
            if (!(v < 0.2f)) is16 = false;
        }
    }

    // ---- LDS staging (one shared copy, 512 threads)
    for (int i = tid; i < 204 * PITCH; i += 512) {
        int r = i / PITCH, k = i - r * PITCH;
        smem[OFF_W1 + i] = (k < H) ? wget(g_Whh1, r * H + k, is16) : 0.f;
    }
    for (int i = tid; i < 153 * PITCH; i += 512) {
        int r = i / PITCH, k = i - r * PITCH;
        smem[OFF_W3 + i] = (k < H) ? wget(g_Wih3, (H + r) * H + k, is16) : 0.f;
    }
    __syncthreads();

    const int kbR = 13 * wid;                                   // register k-slice
    const int kbL = (wid == 0) ? 0 : (wid == 1) ? 12 : (wid == 2) ? 28 : 40;
    const int nbL = (wid == 1) ? 4 : 3;                         // float4 blocks in LDS slice

#define WC(srcp, row, kk) (((kbR + (kk)) < H) ? wget(srcp, (row) * H + kbR + (kk), is16) : 0.f)
#define DECL13(p) float p##_0,p##_1,p##_2,p##_3,p##_4,p##_5,p##_6,p##_7,p##_8,p##_9,p##_10,p##_11,p##_12;
#define LOAD13(p, srcp, row) \
    p##_0 = WC(srcp, row, 0);  p##_1 = WC(srcp, row, 1);  p##_2 = WC(srcp, row, 2); \
    p##_3 = WC(srcp, row, 3);  p##_4 = WC(srcp, row, 4);  p##_5 = WC(srcp, row, 5); \
    p##_6 = WC(srcp, row, 6);  p##_7 = WC(srcp, row, 7);  p##_8 = WC(srcp, row, 8); \
    p##_9 = WC(srcp, row, 9);  p##_10 = WC(srcp, row, 10); p##_11 = WC(srcp, row, 11); \
    p##_12 = WC(srcp, row, 12);

    DECL13(wih2g0) DECL13(wih2g1) DECL13(wih2g2) DECL13(wih2g3)
    DECL13(whh2g0) DECL13(whh2g1) DECL13(whh2g2) DECL13(whh2g3)
    DECL13(whh3g0) DECL13(whh3g1) DECL13(whh3g2) DECL13(whh3g3)
    DECL13(wih3i)
    LOAD13(wih2g0, g_Wih2, 0 * H + jeff) LOAD13(wih2g1, g_Wih2, 1 * H + jeff)
    LOAD13(wih2g2, g_Wih2, 2 * H + jeff) LOAD13(wih2g3, g_Wih2, 3 * H + jeff)
    LOAD13(whh2g0, g_Whh2, 0 * H + jeff) LOAD13(whh2g1, g_Whh2, 1 * H + jeff)
    LOAD13(whh2g2, g_Whh2, 2 * H + jeff) LOAD13(whh2g3, g_Whh2, 3 * H + jeff)
    LOAD13(whh3g0, g_Whh3, 0 * H + jeff) LOAD13(whh3g1, g_Whh3, 1 * H + jeff)
    LOAD13(whh3g2, g_Whh3, 2 * H + jeff) LOAD13(whh3g3, g_Whh3, 3 * H + jeff)
    LOAD13(wih3i,  g_Wih3, 0 * H + jeff)

    const float b1_0 = wget(g_bih1, 0*H+jeff, is16) + wget(g_bhh1, 0*H+jeff, is16);
    const float b1_1 = wget(g_bih1, 1*H+jeff, is16) + wget(g_bhh1, 1*H+jeff, is16);
    const float b1_2 = wget(g_bih1, 2*H+jeff, is16) + wget(g_bhh1, 2*H+jeff, is16);
    const float b1_3 = wget(g_bih1, 3*H+jeff, is16) + wget(g_bhh1, 3*H+jeff, is16);
    const float b2_0 = wget(g_bih2, 0*H+jeff, is16) + wget(g_bhh2, 0*H+jeff, is16);
    const float b2_1 = wget(g_bih2, 1*H+jeff, is16) + wget(g_bhh2, 1*H+jeff, is16);
    const float b2_2 = wget(g_bih2, 2*H+jeff, is16) + wget(g_bhh2, 2*H+jeff, is16);
    const float b2_3 = wget(g_bih2, 3*H+jeff, is16) + wget(g_bhh2, 3*H+jeff, is16);
    const float b3_0 = wget(g_bih3, 0*H+jeff, is16) + wget(g_bhh3, 0*H+jeff, is16);
    const float b3_1 = wget(g_bih3, 1*H+jeff, is16) + wget(g_bhh3, 1*H+jeff, is16);
    const float b3_2 = wget(g_bih3, 2*H+jeff, is16) + wget(g_bhh3, 2*H+jeff, is16);
    const float b3_3 = wget(g_bih3, 3*H+jeff, is16) + wget(g_bhh3, 3*H+jeff, is16);
    const float wi1_0 = wget(g_Wih1, 0*H+jeff, is16);
    const float wi1_1 = wget(g_Wih1, 1*H+jeff, is16);
    const float wi1_2 = wget(g_Wih1, 2*H+jeff, is16);
    const float wi1_3 = wget(g_Wih1, 3*H+jeff, is16);
    const float wlinr = (lane < H) ? wget(g_Wlin, lane, is16) : 0.f;
    const float blinr = wget(g_blin, 0, is16);

    const float4* A1g0 = (const float4*)(smem + OFF_W1 + (0*H + jeff) * PITCH + kbL);
    const float4* A1g1 = (const float4*)(smem + OFF_W1 + (1*H + jeff) * PITCH + kbL);
    const float4* A1g2 = (const float4*)(smem + OFF_W1 + (2*H + jeff) * PITCH + kbL);
    const float4* A1g3 = (const float4*)(smem + OFF_W1 + (3*H + jeff) * PITCH + kbL);
    const float4* A3f  = (const float4*)(smem + OFF_W3 + (      jeff) * PITCH + kbL);
    const float4* A3g  = (const float4*)(smem + OFF_W3 + (H   + jeff) * PITCH + kbL);
    const float4* A3o  = (const float4*)(smem + OFF_W3 + (2*H + jeff) * PITCH + kbL);
    float4* ebufP = (float4*)(smem + OFF_P) + team * (2 * 4 * PITCH);  // team-local
    float*  hbuf  = smem + OFF_H + team * (2 * PITCH);                 // team-local

    float h1_0=0.f,h1_1=0.f,h2_0=0.f,h2_1=0.f,h3_0=0.f,h3_1=0.f;
    float c1my=0.f,c2my=0.f,c3my=0.f;      // live in roles 0/2 only
    float xf0=0.f,xf1=0.f;                 // role 3 only

    const unsigned short* in16 = (const unsigned short*)g_in;
    const float*          in32 = (const float*)g_in;
    unsigned short* o16w0 = (unsigned short*)g_out + (size_t)(eb+0)*T_TOT;
    unsigned short* o16w1 = (unsigned short*)g_out + (size_t)(eb+1)*T_TOT;
    float* o32w0 = (float*)g_out + (size_t)(eb+0)*T_TOT;
    float* o32w1 = (float*)g_out + (size_t)(eb+1)*T_TOT;

#define P2(kk) { \
    float s0_ = rl(h1_0, kbR+(kk)), s1_ = rl(h1_1, kbR+(kk)); \
    float r0_ = rl(h2_0, kbR+(kk)), r1_ = rl(h2_1, kbR+(kk)); \
    a0_0=fmaf(wih2g0_##kk,s0_,a0_0); a0_1=fmaf(wih2g0_##kk,s1_,a0_1); \
    a1_0=fmaf(wih2g1_##kk,s0_,a1_0); a1_1=fmaf(wih2g1_##kk,s1_,a1_1); \
    a2_0=fmaf(wih2g2_##kk,s0_,a2_0); a2_1=fmaf(wih2g2_##kk,s1_,a2_1); \
    a3_0=fmaf(wih2g3_##kk,s0_,a3_0); a3_1=fmaf(wih2g3_##kk,s1_,a3_1); \
    a0_0=fmaf(whh2g0_##kk,r0_,a0_0); a0_1=fmaf(whh2g0_##kk,r1_,a0_1); \
    a1_0=fmaf(whh2g1_##kk,r0_,a1_0); a1_1=fmaf(whh2g1_##kk,r1_,a1_1); \
    a2_0=fmaf(whh2g2_##kk,r0_,a2_0); a2_1=fmaf(whh2g2_##kk,r1_,a2_1); \
    a3_0=fmaf(whh2g3_##kk,r0_,a3_0); a3_1=fmaf(whh2g3_##kk,r1_,a3_1); }

#define P3(kk) { \
    float s0_ = rl(h2_0, kbR+(kk)), s1_ = rl(h2_1, kbR+(kk)); \
    float r0_ = rl(h3_0, kbR+(kk)), r1_ = rl(h3_1, kbR+(kk)); \
    a0_0=fmaf(wih3i_##kk,s0_,a0_0);  a0_1=fmaf(wih3i_##kk,s1_,a0_1); \
    a0_0=fmaf(whh3g0_##kk,r0_,a0_0); a0_1=fmaf(whh3g0_##kk,r1_,a0_1); \
    a1_0=fmaf(whh3g1_##kk,r0_,a1_0); a1_1=fmaf(whh3g1_##kk,r1_,a1_1); \
    a2_0=fmaf(whh3g2_##kk,r0_,a2_0); a2_1=fmaf(whh3g2_##kk,r1_,a2_1); \
    a3_0=fmaf(whh3g3_##kk,r0_,a3_0); a3_1=fmaf(whh3g3_##kk,r1_,a3_1); }

    // exchange partials (team-local buffers, block-wide barrier);
    // roles 0/2 reduce+UPD for elem 0/1; h rebroadcast via LDS
#define EXCHL(hv0, hv1, cmy) { \
    if (lane < H) { \
        ebufP[(0*4 + wid)*PITCH + lane] = make_float4(a0_0, a1_0, a2_0, a3_0); \
        ebufP[(1*4 + wid)*PITCH + lane] = make_float4(a0_1, a1_1, a2_1, a3_1); \
    } \
    __syncthreads(); \
    if ((wid & 1) == 0) { \
        const float4* pb_ = ebufP + (wid >> 1) * 4 * PITCH; \
        float4 q_ = pb_[0*PITCH + jeff]; \
        float4 t_ = pb_[1*PITCH + jeff]; q_.x+=t_.x; q_.y+=t_.y; q_.z+=t_.z; q_.w+=t_.w; \
        t_ = pb_[2*PITCH + jeff]; q_.x+=t_.x; q_.y+=t_.y; q_.z+=t_.z; q_.w+=t_.w; \
        t_ = pb_[3*PITCH + jeff]; q_.x+=t_.x; q_.y+=t_.y; q_.z+=t_.z; q_.w+=t_.w; \
        float ig_ = sigm(q_.x), fg_ = sigm(q_.y), gg_ = tanh_f(q_.z), og_ = sigm(q_.w); \
        cmy = fg_ * cmy + ig_ * gg_; \
        float hn_ = og_ * tanh_f(cmy); \
        if (lane < H) hbuf[(wid >> 1) * PITCH + lane] = hn_; \
    } \
    __syncthreads(); \
    hv0 = hbuf[0*PITCH + jeff]; \
    hv1 = hbuf[1*PITCH + jeff]; }

#pragma clang loop unroll(disable)
    for (int t = 0; t < T_TOT; ++t) {
        float a0_0,a1_0,a2_0,a3_0,a0_1,a1_1,a2_1,a3_1;

        // ---------------- layer 1 ----------------
        if (wid == 3) {
            float x0, x1;
            if (t < T_IN) {
                if (is16) {
                    x0 = bf2f(in16[(size_t)(eb+0)*T_IN + t]);
                    x1 = bf2f(in16[(size_t)(eb+1)*T_IN + t]);
                } else {
                    x0 = in32[(size_t)(eb+0)*T_IN + t];
                    x1 = in32[(size_t)(eb+1)*T_IN + t];
                }
            } else { x0 = xf0; x1 = xf1; }
            a0_0 = fmaf(wi1_0, x0, b1_0); a0_1 = fmaf(wi1_0, x1, b1_0);
            a1_0 = fmaf(wi1_1, x0, b1_1); a1_1 = fmaf(wi1_1, x1, b1_1);
            a2_0 = fmaf(wi1_2, x0, b1_2); a2_1 = fmaf(wi1_2, x1, b1_2);
            a3_0 = fmaf(wi1_3, x0, b1_3); a3_1 = fmaf(wi1_3, x1, b1_3);
        } else {
            a0_0=a1_0=a2_0=a3_0=a0_1=a1_1=a2_1=a3_1=0.f;
        }
        for (int b = 0; b < nbL; ++b) {
            float4 u0 = A1g0[b], u1 = A1g1[b], u2 = A1g2[b], u3 = A1g3[b];
#pragma unroll
            for (int i = 0; i < 4; ++i) {
                int k = kbL + 4*b + i;
                float s0 = rl(h1_0, k), s1 = rl(h1_1, k);
                a0_0 = fmaf(f4e(u0,i), s0, a0_0); a0_1 = fmaf(f4e(u0,i), s1, a0_1);
                a1_0 = fmaf(f4e(u1,i), s0, a1_0); a1_1 = fmaf(f4e(u1,i), s1, a1_1);
                a2_0 = fmaf(f4e(u2,i), s0, a2_0); a2_1 = fmaf(f4e(u2,i), s1, a2_1);
                a3_0 = fmaf(f4e(u3,i), s0, a3_0); a3_1 = fmaf(f4e(u3,i), s1, a3_1);
            }
        }
        EXCHL(h1_0, h1_1, c1my)

        // ---------------- layer 2 ----------------
        if (wid == 3) {
            a0_0=a0_1=b2_0; a1_0=a1_1=b2_1; a2_0=a2_1=b2_2; a3_0=a3_1=b2_3;
        } else {
            a0_0=a1_0=a2_0=a3_0=a0_1=a1_1=a2_1=a3_1=0.f;
        }
        L13(P2)
        EXCHL(h2_0, h2_1, c2my)

        // ---------------- layer 3 ----------------
        if (wid == 3) {
            a0_0=a0_1=b3_0; a1_0=a1_1=b3_1; a2_0=a2_1=b3_2; a3_0=a3_1=b3_3;
        } else {
            a0_0=a1_0=a2_0=a3_0=a0_1=a1_1=a2_1=a3_1=0.f;
        }
        for (int b = 0; b < nbL; ++b) {
            float4 uf = A3f[b], ug = A3g[b], uo = A3o[b];
#pragma unroll
            for (int i = 0; i < 4; ++i) {
                int k = kbL + 4*b + i;
                float s0 = rl(h2_0, k), s1 = rl(h2_1, k);
                a1_0 = fmaf(f4e(uf,i), s0, a1_0); a1_1 = fmaf(f4e(uf,i), s1, a1_1);
                a2_0 = fmaf(f4e(ug,i), s0, a2_0); a2_1 = fmaf(f4e(ug,i), s1, a2_1);
                a3_0 = fmaf(f4e(uo,i), s0, a3_0); a3_1 = fmaf(f4e(uo,i), s1, a3_1);
            }
        }
        L13(P3)
        EXCHL(h3_0, h3_1, c3my)

        // ---------------- head: role-3 wave of each team ----------------
        if (wid == 3) {
            float s0 = wlinr * h3_0; RED(s0) float ov0 = s0 + blinr;
            float s1 = wlinr * h3_1; RED(s1) float ov1 = s1 + blinr;
            xf0 = ov0; xf1 = ov1;
            if (lane == 0) {
                if (is16) { o16w0[t] = f2bf(ov0); o16w1[t] = f2bf(ov1); }
                else      { o32w0[t] = ov0;       o32w1[t] = ov1; }
            }
        }
    }
}

extern "C" void kernel_launch(void* const* d_in, const int* in_sizes, int n_in,
                              void* d_out, int out_size, void* d_ws, size_t ws_size,
                              hipStream_t stream) {
    (void)in_sizes; (void)n_in; (void)d_ws; (void)ws_size; (void)out_size;
    size_t shmem = LDSFL * sizeof(float);   // 88,400 B -> 1 block/CU, grid 256 = #CUs
    hipFuncSetAttribute((const void*)lstm3_kernel,
                        hipFuncAttributeMaxDynamicSharedMemorySize, (int)shmem);
    lstm3_kernel<<<dim3(256), dim3(512), shmem, stream>>>(
        d_in[0],  d_in[1],  d_in[2],  d_in[3],  d_in[4],
        d_in[5],  d_in[6],  d_in[7],  d_in[8],
        d_in[9],  d_in[10], d_in[11], d_in[12],
        d_in[13], d_in[14], d_out);
}